// Round 1
// baseline (295.272 us; speedup 1.0000x reference)
//
#include <hip/hip_runtime.h>
#include <math.h>

#define S1C 10
#define S2C 25
#define DC 128
#define NSAMP 261
#define NBATCH 2048
#define FEA_SZ (128*2048)

__device__ __forceinline__ float lrelu(float v) { return v > 0.f ? v : 0.01f * v; }
__device__ __forceinline__ float sigm(float v) { return 1.f / (1.f + __expf(-v)); }

// ws[0:128)=a1=V1h1a^T w1[:128], ws[128:256)=a2=V1h1a^T w1[128:],
// ws[256:384)=b1=V1h0a^T w0[:128], ws[384:512)=b2=V1h0a^T w0[128:]
__global__ void prep_kernel(const float* __restrict__ Vh1a, const float* __restrict__ w1,
                            const float* __restrict__ Vh0a, const float* __restrict__ w0,
                            float* __restrict__ ws) {
    int tid = threadIdx.x;
    for (int o = tid; o < 512; o += 256) {
        int which = o >> 7, n = o & 127;
        const float* V = (which < 2) ? Vh1a : Vh0a;
        const float* w = (which < 2) ? w1 : w0;
        int off = (which & 1) * 128;
        float acc = 0.f;
        for (int l = 0; l < 128; ++l) acc += V[l * 128 + n] * w[off + l];
        ws[o] = acc;
    }
}

__global__ __launch_bounds__(256, 2) void agg_kernel(
    const float* __restrict__ x, const int* __restrict__ samples,
    const float* __restrict__ V1h1, const float* __restrict__ V1h0,
    const float* __restrict__ Whops, const float* __restrict__ ws,
    float* __restrict__ out)
{
    const int b = blockIdx.x;
    const int tid = threadIdx.x;
    const int g = tid >> 5, lane = tid & 31;

    __shared__ __align__(16) float sA1[128];
    __shared__ __align__(16) float sA2[128];
    __shared__ __align__(16) float sB1[128];
    __shared__ __align__(16) float sB2[128];
    __shared__ __align__(16) float sT0[128];
    __shared__ __align__(16) float sT1[10][128];
    __shared__ float sC1[10], sD1[10], sC0[1], sBeta0[10];
    __shared__ __align__(16) float sNbr[50][132];   // +4 pad breaks bank conflicts
    __shared__ float sD2[50];
    __shared__ float sBeta1[2][25];
    __shared__ __align__(16) float sAggF[10][128];
    __shared__ __align__(16) float sEmbT1[10][128];
    __shared__ __align__(16) float sAgg1[10][128];
    __shared__ __align__(16) float sEmbT0[128];
    __shared__ __align__(16) float sAgg0[128];
    __shared__ __align__(16) float sHop1[10][128];
    __shared__ __align__(16) float sHop0[128];
    __shared__ float sLog[12];
    __shared__ float sBetaH[10];
    __shared__ __align__(16) float sHopH[128];
    __shared__ int sIdx[NSAMP];

    if (tid < 128) { sA1[tid] = ws[tid]; sA2[tid] = ws[128 + tid]; }
    else { int t2 = tid - 128; sB1[t2] = ws[256 + t2]; sB2[t2] = ws[384 + t2]; }
    for (int i = tid; i < NSAMP; i += 256) sIdx[i] = samples[(size_t)b * NSAMP + i];
    __syncthreads();

    // ---- stage fea_t1 (rows 0..9) + fea_t0 (row 10), fused a1/a2 dots ----
    for (int round = 0; round < 2; ++round) {
        int r = round * 8 + g;
        float p1 = 0.f, p2 = 0.f;
        if (r < 11) {
            int node = (r < 10) ? sIdx[1 + r] : sIdx[0];
            float4 v = *(const float4*)(x + (size_t)node * DC + lane * 4);
            float4 a1v = *(const float4*)(sA1 + lane * 4);
            float4 a2v = *(const float4*)(sA2 + lane * 4);
            float* dst = (r < 10) ? &sT1[r][0] : &sT0[0];
            *(float4*)(dst + lane * 4) = v;
            p1 = v.x * a1v.x + v.y * a1v.y + v.z * a1v.z + v.w * a1v.w;
            p2 = v.x * a2v.x + v.y * a2v.y + v.z * a2v.z + v.w * a2v.w;
        }
        for (int o = 16; o > 0; o >>= 1) { p1 += __shfl_xor(p1, o, 32); p2 += __shfl_xor(p2, o, 32); }
        if (r < 11 && lane == 0) {
            if (r < 10) { sC1[r] = p1; sD1[r] = p2; }
            else sC0[0] = p1;
        }
    }
    __syncthreads();

    // ---- beta0 = softmax_s(lrelu(c0 + d1[s])) ----
    if (tid < 16) {
        float v = (tid < 10) ? lrelu(sC0[0] + sD1[tid]) : -3.4e38f;
        float m = v;
        for (int o = 8; o > 0; o >>= 1) m = fmaxf(m, __shfl_xor(m, o, 16));
        float e = (tid < 10) ? __expf(v - m) : 0.f;
        float ssum = e;
        for (int o = 8; o > 0; o >>= 1) ssum += __shfl_xor(ssum, o, 16);
        if (tid < 10) sBeta0[tid] = e / ssum;
    }

    // ---- neighbor loop: 5 pairs of s, each stages 50 rows of fea_n2 ----
    for (int pair = 0; pair < 5; ++pair) {
        __syncthreads();  // protect sNbr/sD2/sBeta1 from previous readers
        for (int round = 0; round < 7; ++round) {
            int r = round * 8 + g;
            float p2 = 0.f;
            if (r < 50) {
                int s = pair * 2 + (r / 25);
                int t = r % 25;
                int node = sIdx[11 + s * S2C + t];
                float4 v = *(const float4*)(x + (size_t)node * DC + lane * 4);
                float4 a2v = *(const float4*)(sA2 + lane * 4);
                *(float4*)(&sNbr[r][lane * 4]) = v;
                p2 = v.x * a2v.x + v.y * a2v.y + v.z * a2v.z + v.w * a2v.w;
            }
            for (int o = 16; o > 0; o >>= 1) p2 += __shfl_xor(p2, o, 32);
            if (r < 50 && lane == 0) sD2[r] = p2;
        }
        __syncthreads();
        if (g < 2) {  // two 32-lane groups do the two softmaxes over 25
            int s = pair * 2 + g;
            float v = (lane < 25) ? lrelu(sC1[s] + sD2[g * 25 + lane]) : -3.4e38f;
            float m = v;
            for (int o = 16; o > 0; o >>= 1) m = fmaxf(m, __shfl_xor(m, o, 32));
            float e = (lane < 25) ? __expf(v - m) : 0.f;
            float ssum = e;
            for (int o = 16; o > 0; o >>= 1) ssum += __shfl_xor(ssum, o, 32);
            if (lane < 25) {
                float bt = e / ssum;
                sBeta1[g][lane] = bt;
                out[FEA_SZ + (size_t)b * 260 + s * 26 + 1 + lane] = bt;
            }
        }
        __syncthreads();
        {   // agg_feat[s][n] = sum_t beta1[s][t] * fea_n2[s][t][n]
            int h = tid >> 7, n = tid & 127;
            int s = pair * 2 + h;
            float acc = 0.f;
            #pragma unroll
            for (int t = 0; t < 25; ++t) acc += sBeta1[h][t] * sNbr[h * 25 + t][n];
            sAggF[s][n] = acc;
        }
    }
    __syncthreads();

    // ---- V1_h1 pass: emb_t1[s], agg1[s], emb_t0 ----
    {
        int l = tid & 127, h = tid >> 7;
        float accE[5] = {0, 0, 0, 0, 0};
        float accA[5] = {0, 0, 0, 0, 0};
        float accT0 = 0.f;
        const float* Vrow = V1h1 + (size_t)l * DC;
        for (int k = 0; k < 32; ++k) {
            float4 w4 = *(const float4*)(Vrow + k * 4);
            float wv[4] = {w4.x, w4.y, w4.z, w4.w};
            #pragma unroll
            for (int j = 0; j < 4; ++j) {
                int n = k * 4 + j;
                float w = wv[j];
                if (h == 0) accT0 += w * sT0[n];
                #pragma unroll
                for (int s5 = 0; s5 < 5; ++s5) {
                    accE[s5] += w * sT1[h * 5 + s5][n];
                    accA[s5] += w * sAggF[h * 5 + s5][n];
                }
            }
        }
        #pragma unroll
        for (int s5 = 0; s5 < 5; ++s5) { sEmbT1[h * 5 + s5][l] = accE[s5]; sAgg1[h * 5 + s5][l] = accA[s5]; }
        if (h == 0) sEmbT0[l] = accT0;
    }
    __syncthreads();

    // ---- agg0[n] = sum_s beta0[s] emb_t1[s][n] ----
    if (tid < 128) {
        float acc = 0.f;
        #pragma unroll
        for (int s = 0; s < 10; ++s) acc += sBeta0[s] * sEmbT1[s][tid];
        sAgg0[tid] = acc;
    }
    __syncthreads();

    // ---- W_hops pass: hop1[s] = sigmoid(W1 emb_t1[s] + W2 agg1[s]); hop0 likewise ----
    {
        int d = tid & 127, h = tid >> 7;
        float acc1[5] = {0, 0, 0, 0, 0};
        float acc0 = 0.f;
        const float* Wrow = Whops + (size_t)d * 256;
        for (int k = 0; k < 32; ++k) {
            float4 wa4 = *(const float4*)(Wrow + k * 4);
            float4 wb4 = *(const float4*)(Wrow + 128 + k * 4);
            float wa[4] = {wa4.x, wa4.y, wa4.z, wa4.w};
            float wb[4] = {wb4.x, wb4.y, wb4.z, wb4.w};
            #pragma unroll
            for (int j = 0; j < 4; ++j) {
                int n = k * 4 + j;
                #pragma unroll
                for (int s5 = 0; s5 < 5; ++s5) {
                    acc1[s5] += wa[j] * sEmbT1[h * 5 + s5][n] + wb[j] * sAgg1[h * 5 + s5][n];
                }
                if (h == 1) acc0 += wa[j] * sEmbT0[n] + wb[j] * sAgg0[n];
            }
        }
        #pragma unroll
        for (int s5 = 0; s5 < 5; ++s5) sHop1[h * 5 + s5][d] = sigm(acc1[s5]);
        if (h == 1) sHop0[d] = sigm(acc0);
    }
    __syncthreads();

    // ---- logits_h: sLog[s] = hop1[s].b2 (s<10), sLog[10] = hop0.b1 ----
    for (int round = 0; round < 2; ++round) {
        int r = round * 8 + g;
        float p = 0.f;
        if (r < 11) {
            const float* src = (r < 10) ? &sHop1[r][0] : &sHop0[0];
            const float* vec = (r < 10) ? sB2 : sB1;
            float4 hv = *(const float4*)(src + lane * 4);
            float4 bv = *(const float4*)(vec + lane * 4);
            p = hv.x * bv.x + hv.y * bv.y + hv.z * bv.z + hv.w * bv.w;
        }
        for (int o = 16; o > 0; o >>= 1) p += __shfl_xor(p, o, 32);
        if (r < 11 && lane == 0) sLog[r] = p;
    }
    __syncthreads();

    // ---- beta_h softmax over s ----
    if (tid < 16) {
        float v = (tid < 10) ? lrelu(sLog[10] + sLog[tid]) : -3.4e38f;
        float m = v;
        for (int o = 8; o > 0; o >>= 1) m = fmaxf(m, __shfl_xor(m, o, 16));
        float e = (tid < 10) ? __expf(v - m) : 0.f;
        float ssum = e;
        for (int o = 8; o > 0; o >>= 1) ssum += __shfl_xor(ssum, o, 16);
        if (tid < 10) {
            float bh = e / ssum;
            sBetaH[tid] = bh;
            out[FEA_SZ + (size_t)b * 260 + tid * 26] = bh;
        }
    }
    __syncthreads();

    // ---- hop_h[n] = sum_s beta_h[s] hop1[s][n] ----
    if (tid < 128) {
        float acc = 0.f;
        #pragma unroll
        for (int s = 0; s < 10; ++s) acc += sBetaH[s] * sHop1[s][tid];
        sHopH[tid] = acc;
    }
    __syncthreads();

    // ---- fea_out[l] = sum_d hop_h[d] V1h0[l][d]; out is fea_out^T ----
    if (tid < 128) {
        const float* Vrow = V1h0 + (size_t)tid * DC;
        float acc = 0.f;
        for (int k = 0; k < 32; ++k) {
            float4 w4 = *(const float4*)(Vrow + k * 4);
            acc += w4.x * sHopH[k * 4] + w4.y * sHopH[k * 4 + 1] + w4.z * sHopH[k * 4 + 2] + w4.w * sHopH[k * 4 + 3];
        }
        out[(size_t)tid * 2048 + b] = acc;
    }
}

extern "C" void kernel_launch(void* const* d_in, const int* in_sizes, int n_in,
                              void* d_out, int out_size, void* d_ws, size_t ws_size,
                              hipStream_t stream) {
    const float* x      = (const float*)d_in[0];
    const int*   samples= (const int*)d_in[1];
    const float* V1h1a  = (const float*)d_in[2];
    const float* w1h1   = (const float*)d_in[3];
    const float* V1h0a  = (const float*)d_in[4];
    const float* w1h0   = (const float*)d_in[5];
    const float* V1h1   = (const float*)d_in[6];
    const float* V1h0   = (const float*)d_in[7];
    const float* Whops  = (const float*)d_in[8];
    float* outp = (float*)d_out;
    float* ws   = (float*)d_ws;

    hipLaunchKernelGGL(prep_kernel, dim3(1), dim3(256), 0, stream, V1h1a, w1h1, V1h0a, w1h0, ws);
    hipLaunchKernelGGL(agg_kernel, dim3(2048), dim3(256), 0, stream,
                       x, samples, V1h1, V1h0, Whops, ws, outp);
}

// Round 2
// 170.434 us; speedup vs baseline: 1.7325x; 1.7325x over previous
//
#include <hip/hip_runtime.h>
#include <math.h>

#define S1C 10
#define S2C 25
#define DC 128
#define NSAMP 261
#define NBATCH 2048
#define FEA_SZ (128*2048)

// ws layout (floats):
//   [0:128)    a1 = V1h1a^T w1[:128]
//   [128:256)  a2 = V1h1a^T w1[128:]
//   [256:384)  b1 = V1h0a^T w0[:128]
//   [384:512)  b2 = V1h0a^T w0[128:]
//   [512:512+16384)        W1V = Whops[:,:128] @ V1h1   (row-major [128][128])
//   [512+16384:512+32768)  W2V = Whops[:,128:] @ V1h1   (row-major [128][128])
//   [512+32768: +2048*10*128) aggF[b][s][n]
#define WS_WV   512
#define WS_AGGF (512 + 2*128*128)

__device__ __forceinline__ float lrelu(float v) { return v > 0.f ? v : 0.01f * v; }
__device__ __forceinline__ float sigm(float v) { return 1.f / (1.f + __expf(-v)); }

__global__ void prep_kernel(const float* __restrict__ Vh1a, const float* __restrict__ w1,
                            const float* __restrict__ Vh0a, const float* __restrict__ w0,
                            float* __restrict__ ws) {
    int tid = threadIdx.x;
    for (int o = tid; o < 512; o += 256) {
        int which = o >> 7, n = o & 127;
        const float* V = (which < 2) ? Vh1a : Vh0a;
        const float* w = (which < 2) ? w1 : w0;
        int off = (which & 1) * 128;
        float acc = 0.f;
        for (int l = 0; l < 128; ++l) acc += V[l * 128 + n] * w[off + l];
        ws[o] = acc;
    }
}

// W1V[d][n] = sum_j Whops[d][j]     * V1h1[j][n]
// W2V[d][n] = sum_j Whops[d][128+j] * V1h1[j][n]
// grid(128), block(256): each block does 2 row-tasks (task = blk*2 + h)
__global__ void prepWV_kernel(const float* __restrict__ V1h1,
                              const float* __restrict__ Whops,
                              float* __restrict__ ws) {
    int h = threadIdx.x >> 7, n = threadIdx.x & 127;
    int task = blockIdx.x * 2 + h;          // 0..255
    int which = task >> 7, d = task & 127;  // which: 0 -> W1V, 1 -> W2V
    const float* Wrow = Whops + (size_t)d * 256 + which * 128;
    float acc = 0.f;
    for (int j = 0; j < 128; ++j) acc += Wrow[j] * V1h1[(size_t)j * 128 + n];
    ws[WS_WV + (size_t)task * 128 + n] = acc;
}

// One block per (b,s): grid = dim3(10, 2048). Computes beta1[b][s][:] and
// aggF[b][s][n] = sum_t beta1[t] * x[idx2[b][s][t]][n].
__global__ __launch_bounds__(256) void nbr_kernel(
    const float* __restrict__ x, const int* __restrict__ samples,
    const float* __restrict__ ws, float* __restrict__ aggF,
    float* __restrict__ out)
{
    const int s = blockIdx.x, b = blockIdx.y;
    const int tid = threadIdx.x, g = tid >> 5, lane = tid & 31;

    __shared__ __align__(16) float sNbr[25][132];
    __shared__ float sD[26];
    __shared__ float sBeta[25];

    // a1 (for c1 = t1.a1) and a2 (for d2 = nbr.a2) fragments in registers
    float4 a1v = *(const float4*)(ws + lane * 4);
    float4 a2v = *(const float4*)(ws + 128 + lane * 4);
    const int* sidx = samples + (size_t)b * NSAMP;

    for (int round = 0; round < 4; ++round) {
        int r = round * 8 + g;          // rows 0..24: neighbors; row 25: fea_t1[s]
        float p = 0.f;
        if (r < 26) {
            int node = (r < 25) ? sidx[11 + s * S2C + r] : sidx[1 + s];
            float4 v = *(const float4*)(x + (size_t)node * DC + lane * 4);
            if (r < 25) *(float4*)(&sNbr[r][lane * 4]) = v;
            float4 av = (r < 25) ? a2v : a1v;
            p = v.x * av.x + v.y * av.y + v.z * av.z + v.w * av.w;
        }
        for (int o = 16; o > 0; o >>= 1) p += __shfl_xor(p, o, 32);
        if (r < 26 && lane == 0) sD[r] = p;
    }
    __syncthreads();

    if (tid < 32) {
        float c1 = sD[25];
        float v = (lane < 25) ? lrelu(c1 + sD[lane]) : -3.4e38f;
        float m = v;
        for (int o = 16; o > 0; o >>= 1) m = fmaxf(m, __shfl_xor(m, o, 32));
        float e = (lane < 25) ? __expf(v - m) : 0.f;
        float ssum = e;
        for (int o = 16; o > 0; o >>= 1) ssum += __shfl_xor(ssum, o, 32);
        if (lane < 25) {
            float bt = e / ssum;
            sBeta[lane] = bt;
            out[FEA_SZ + (size_t)b * 260 + s * 26 + 1 + lane] = bt;
        }
    }
    __syncthreads();

    if (tid < 128) {
        float acc = 0.f;
        #pragma unroll
        for (int t = 0; t < 25; ++t) acc += sBeta[t] * sNbr[t][tid];
        aggF[((size_t)b * 10 + s) * 128 + tid] = acc;
    }
}

// One block per b. Uses precomputed W1V/W2V so no emb_t1/agg1 pass is needed:
//   hop1[s] = sigm(W1V. t1[s] + W2V. aggF[s])
//   hop0    = sigm(W1V. t0    + W2V. tbar),  tbar = sum_s beta0[s] t1[s]
__global__ __launch_bounds__(256) void head_kernel(
    const float* __restrict__ x, const int* __restrict__ samples,
    const float* __restrict__ V1h0, const float* __restrict__ ws,
    float* __restrict__ out)
{
    const int b = blockIdx.x;
    const int tid = threadIdx.x, g = tid >> 5, lane = tid & 31;
    const float* WV = ws + WS_WV;
    const float* aggF = ws + WS_AGGF;

    __shared__ __align__(16) float sA1[128], sA2[128], sB1[128], sB2[128];
    __shared__ __align__(16) float sT0[128];
    __shared__ __align__(16) float sT1[10][128];
    __shared__ __align__(16) float sAggF[10][128];
    __shared__ __align__(16) float sTbar[128];
    __shared__ __align__(16) float sHop1[10][128];
    __shared__ __align__(16) float sHop0[128];
    __shared__ __align__(16) float sHopH[128];
    __shared__ float sD1[10], sC0, sBeta0[10], sLog[12], sBetaH[10];
    __shared__ int sIdx[16];

    if (tid < 128) { sA1[tid] = ws[tid]; sA2[tid] = ws[128 + tid]; }
    else { int t2 = tid - 128; sB1[t2] = ws[256 + t2]; sB2[t2] = ws[384 + t2]; }
    if (tid < 11) sIdx[tid] = samples[(size_t)b * NSAMP + tid];
    __syncthreads();

    // stage t1 rows (r<10), t0 (r=10) with fused a1/a2 dots; aggF rows (11<=r<21)
    for (int round = 0; round < 3; ++round) {
        int r = round * 8 + g;
        float p1 = 0.f, p2 = 0.f;
        if (r < 11) {
            int node = (r < 10) ? sIdx[1 + r] : sIdx[0];
            float4 v = *(const float4*)(x + (size_t)node * DC + lane * 4);
            float4 a1v = *(const float4*)(sA1 + lane * 4);
            float4 a2v = *(const float4*)(sA2 + lane * 4);
            float* dst = (r < 10) ? &sT1[r][0] : &sT0[0];
            *(float4*)(dst + lane * 4) = v;
            p1 = v.x * a1v.x + v.y * a1v.y + v.z * a1v.z + v.w * a1v.w;
            p2 = v.x * a2v.x + v.y * a2v.y + v.z * a2v.z + v.w * a2v.w;
        } else if (r < 21) {
            int rr = r - 11;
            float4 v = *(const float4*)(aggF + ((size_t)b * 10 + rr) * 128 + lane * 4);
            *(float4*)(&sAggF[rr][lane * 4]) = v;
        }
        for (int o = 16; o > 0; o >>= 1) { p1 += __shfl_xor(p1, o, 32); p2 += __shfl_xor(p2, o, 32); }
        if (r < 11 && lane == 0) { if (r < 10) sD1[r] = p2; else sC0 = p1; }
    }
    __syncthreads();

    // beta0 = softmax_s(lrelu(c0 + d1[s]))
    if (tid < 16) {
        float v = (tid < 10) ? lrelu(sC0 + sD1[tid]) : -3.4e38f;
        float m = v;
        for (int o = 8; o > 0; o >>= 1) m = fmaxf(m, __shfl_xor(m, o, 16));
        float e = (tid < 10) ? __expf(v - m) : 0.f;
        float ssum = e;
        for (int o = 8; o > 0; o >>= 1) ssum += __shfl_xor(ssum, o, 16);
        if (tid < 10) sBeta0[tid] = e / ssum;
    }
    __syncthreads();

    // tbar[n] = sum_s beta0[s] t1[s][n]
    if (tid < 128) {
        float acc = 0.f;
        #pragma unroll
        for (int s = 0; s < 10; ++s) acc += sBeta0[s] * sT1[s][tid];
        sTbar[tid] = acc;
    }
    __syncthreads();

    // hop pass: hop1[s][d], hop0[d]
    {
        int d = tid & 127, h = tid >> 7;
        float acc1[5] = {0, 0, 0, 0, 0};
        float acc0 = 0.f;
        const float* W1r = WV + (size_t)d * 128;
        const float* W2r = WV + (size_t)(128 + d) * 128;
        for (int k = 0; k < 32; ++k) {
            float4 wa4 = *(const float4*)(W1r + k * 4);
            float4 wb4 = *(const float4*)(W2r + k * 4);
            float wa[4] = {wa4.x, wa4.y, wa4.z, wa4.w};
            float wb[4] = {wb4.x, wb4.y, wb4.z, wb4.w};
            #pragma unroll
            for (int j = 0; j < 4; ++j) {
                int n = k * 4 + j;
                #pragma unroll
                for (int s5 = 0; s5 < 5; ++s5) {
                    acc1[s5] += wa[j] * sT1[h * 5 + s5][n] + wb[j] * sAggF[h * 5 + s5][n];
                }
                if (h == 1) acc0 += wa[j] * sT0[n] + wb[j] * sTbar[n];
            }
        }
        #pragma unroll
        for (int s5 = 0; s5 < 5; ++s5) sHop1[h * 5 + s5][d] = sigm(acc1[s5]);
        if (h == 1) sHop0[d] = sigm(acc0);
    }
    __syncthreads();

    // logits: sLog[s] = hop1[s].b2 (s<10), sLog[10] = hop0.b1
    for (int round = 0; round < 2; ++round) {
        int r = round * 8 + g;
        float p = 0.f;
        if (r < 11) {
            const float* src = (r < 10) ? &sHop1[r][0] : &sHop0[0];
            const float* vec = (r < 10) ? sB2 : sB1;
            float4 hv = *(const float4*)(src + lane * 4);
            float4 bv = *(const float4*)(vec + lane * 4);
            p = hv.x * bv.x + hv.y * bv.y + hv.z * bv.z + hv.w * bv.w;
        }
        for (int o = 16; o > 0; o >>= 1) p += __shfl_xor(p, o, 32);
        if (r < 11 && lane == 0) sLog[r] = p;
    }
    __syncthreads();

    // beta_h softmax over s
    if (tid < 16) {
        float v = (tid < 10) ? lrelu(sLog[10] + sLog[tid]) : -3.4e38f;
        float m = v;
        for (int o = 8; o > 0; o >>= 1) m = fmaxf(m, __shfl_xor(m, o, 16));
        float e = (tid < 10) ? __expf(v - m) : 0.f;
        float ssum = e;
        for (int o = 8; o > 0; o >>= 1) ssum += __shfl_xor(ssum, o, 16);
        if (tid < 10) {
            float bh = e / ssum;
            sBetaH[tid] = bh;
            out[FEA_SZ + (size_t)b * 260 + tid * 26] = bh;
        }
    }
    __syncthreads();

    // hop_h[n] = sum_s beta_h[s] hop1[s][n]
    if (tid < 128) {
        float acc = 0.f;
        #pragma unroll
        for (int s = 0; s < 10; ++s) acc += sBetaH[s] * sHop1[s][tid];
        sHopH[tid] = acc;
    }
    __syncthreads();

    // fea_out[l] = sum_d hop_h[d] V1h0[l][d]; out is fea_out^T
    if (tid < 128) {
        const float* Vrow = V1h0 + (size_t)tid * DC;
        float acc = 0.f;
        for (int k = 0; k < 32; ++k) {
            float4 w4 = *(const float4*)(Vrow + k * 4);
            acc += w4.x * sHopH[k * 4] + w4.y * sHopH[k * 4 + 1] + w4.z * sHopH[k * 4 + 2] + w4.w * sHopH[k * 4 + 3];
        }
        out[(size_t)tid * 2048 + b] = acc;
    }
}

extern "C" void kernel_launch(void* const* d_in, const int* in_sizes, int n_in,
                              void* d_out, int out_size, void* d_ws, size_t ws_size,
                              hipStream_t stream) {
    const float* x      = (const float*)d_in[0];
    const int*   samples= (const int*)d_in[1];
    const float* V1h1a  = (const float*)d_in[2];
    const float* w1h1   = (const float*)d_in[3];
    const float* V1h0a  = (const float*)d_in[4];
    const float* w1h0   = (const float*)d_in[5];
    const float* V1h1   = (const float*)d_in[6];
    const float* V1h0   = (const float*)d_in[7];
    const float* Whops  = (const float*)d_in[8];
    float* outp = (float*)d_out;
    float* ws   = (float*)d_ws;

    hipLaunchKernelGGL(prep_kernel, dim3(1), dim3(256), 0, stream, V1h1a, w1h1, V1h0a, w1h0, ws);
    hipLaunchKernelGGL(prepWV_kernel, dim3(128), dim3(256), 0, stream, V1h1, Whops, ws);
    hipLaunchKernelGGL(nbr_kernel, dim3(10, 2048), dim3(256), 0, stream,
                       x, samples, ws, ws + WS_AGGF, outp);
    hipLaunchKernelGGL(head_kernel, dim3(2048), dim3(256), 0, stream,
                       x, samples, V1h0, ws, outp);
}